// Round 12
// baseline (232.122 us; speedup 1.0000x reference)
//
#include <hip/hip_runtime.h>
#include <math.h>

#define T_DIM 2048
#define B_DIM 96
#define C_DIM 128
#define L_DIM 128
#define LOG2E 1.4426950408889634f
#define LN2 0.69314718055994531f
#define SMOOTH 0.1f
#define SENT (-(1 << 30))       // virgin lane frame (f32-exact power of 2)
#define PH_ROWS 16
#define NPH 128                 // 128 phases x 16 steps cover t = 1..2047

// wave shift-right-by-1, 0-fill — the proven helper (float only).
__device__ __forceinline__ float dpp_shr1_f(float x) {
  return __int_as_float(__builtin_amdgcn_update_dpp(
      0, __float_as_int(x), 0x138 /*WAVE_SR1*/, 0xF, 0xF, true));
}

// R9/R10-proven CTC step math (unchanged).
#define CTC_MATH(k_) do {                                                    \
  const float r3s = dpp_shr1_f(r3);                                          \
  const int   Es  = (int)dpp_shr1_f((float)E);                               \
  const int   be  = (__float_as_int(r3s) >> 23) & 0xFF;                      \
  int diff = (be - 187) + (Es - E);                                          \
  diff = (__float_as_int(r3s) != 0 && diff > 0) ? diff : 0;                  \
  r0 = ldexpf(r0, -diff); r1 = ldexpf(r1, -diff); r2 = ldexpf(r2, -diff);    \
  r3 = ldexpf(r3, -diff); r4 = ldexpf(r4, -diff);                            \
  E += diff;                                                                 \
  const float d3 = ldexpf(r3s, Es - E);                                      \
  const float n0 = (r0 + d3) * pKv;                                          \
  const float n1 = __builtin_fmaf(skA, d3, r0 + r1) * pAv;                   \
  const float n2 = (r2 + r1) * pKv;                                          \
  const float n3 = __builtin_fmaf(skB, r1, r3 + r2) * pBv;                   \
  const float n4 = (r4 + r3) * pKv;                                          \
  r0 = n0; r1 = n1; r2 = n2; r3 = n3; r4 = n4;                               \
  if (((k_) & 3) == 3) {                                                     \
    const float m = fmaxf(fmaxf(fmaxf(r0, r1), fmaxf(r2, r3)), r4);          \
    const int sh2 = (m > 0.0f)                                               \
                      ? (187 - ((__float_as_int(m) >> 23) & 0xFF)) : 0;      \
    r0 = ldexpf(r0, sh2); r1 = ldexpf(r1, sh2); r2 = ldexpf(r2, sh2);        \
    r3 = ldexpf(r3, sh2); r4 = ldexpf(r4, sh2);                              \
    E -= sh2;                                                                \
  }                                                                          \
} while (0)

// Continuous prefetch, R10-style: compile-time pc/pn select, never cut.
#define CTC_STEP(k_) do {                                                    \
  const float pAv = fA[(k_) & 3], pBv = fB[(k_) & 3], pKv = fK[(k_) & 3];    \
  const int kn = (k_) + 4;                                                   \
  const float* nr = (kn < PH_ROWS) ? (pc + kn * C_DIM)                       \
                                   : (pn + (kn - PH_ROWS) * C_DIM);          \
  fA[(k_) & 3] = nr[tgA]; fB[(k_) & 3] = nr[tgB]; fK[(k_) & 3] = nr[0];      \
  CTC_MATH(k_);                                                              \
} while (0)

// One block (512 thr, 8 waves) per TWO samples. half = tid>>8.
//   Per half: wave (tid_h<64) = CTC consumer; 3 waves = producers.
//   Consumers are block-waves 0 and 4 -> same SIMD (if wave%4 mapping):
//   two independent dependency chains interleave.
//   Per-half 3-deep ring of 16-row buffers (48 KB total) — R10's proven
//   continuous-pipeline structure, phase size halved.
__global__ __launch_bounds__(512) void ctc_fused_kernel(
    const float* __restrict__ lp, const int* __restrict__ targets,
    const int* __restrict__ in_len, const int* __restrict__ tg_len,
    float* __restrict__ ws)
{
  const int tid   = threadIdx.x;
  const int half  = tid >> 8;                      // 0 or 1
  const int tid_h = tid & 255;
  const int b     = blockIdx.x * 2 + half;
  const size_t RSTR = (size_t)B_DIM * C_DIM;       // floats per t-row
  const int Tb = in_len[b];
  const float* base = lp + (size_t)b * C_DIM;

  __shared__ float rows[2][3][PH_ROWS][C_DIM];     // 48 KB

  // consumer state
  int tgA = 0, tgB = 0;
  float skA = 0.f, skB = 0.f;
  float r0 = 0.f, r1 = 0.f, r2 = 0.f, r3 = 0.f, r4 = 0.f;
  int E = SENT;
  float fA[4], fB[4], fK[4];
  float klacc = 0.f;                               // producers only

  if (tid_h < 64) {
    const int l = tid_h;
    tgA = targets[b * L_DIM + 2 * l];
    tgB = targets[b * L_DIM + 2 * l + 1];
    skA = (l > 0 && tgA != targets[b * L_DIM + 2 * l - 1]) ? 1.f : 0.f;
    skB = (tgB != tgA) ? 1.f : 0.f;
    if (l == 0) {
      r0 = __builtin_amdgcn_exp2f(base[0]   * LOG2E);
      r1 = __builtin_amdgcn_exp2f(base[tgA] * LOG2E);
      E = 0;
    }
  } else {
    // prefill bufs 0,1 with rows t=1..32 (as probs); KL for t=0..32
    const int ptid = tid_h - 64;                   // 0..191
    #pragma unroll
    for (int i = 0; i < 6; ++i) {
      const int task = i * 192 + ptid;             // 32 rows x 32 float4
      if (task < 1024) {
        const int row = task >> 5;                 // 0..31 ; t = 1+row
        const int c4  = task & 31;
        const int t   = 1 + row;
        const float4 v = *(const float4*)(base + (size_t)t * RSTR + c4 * 4);
        float4 w;
        w.x = __builtin_amdgcn_exp2f(v.x * LOG2E);
        w.y = __builtin_amdgcn_exp2f(v.y * LOG2E);
        w.z = __builtin_amdgcn_exp2f(v.z * LOG2E);
        w.w = __builtin_amdgcn_exp2f(v.w * LOG2E);
        *(float4*)&rows[half][row >> 4][row & 15][c4 * 4] = w;
        if (t < Tb) {
          float s = v.x + v.y + v.z + v.w;
          if (c4 == 0) s -= v.x;
          klacc += s;
        }
      }
    }
    if (ptid < 32 && 0 < Tb) {                     // row t=0 KL contribution
      const float4 v = *(const float4*)(base + ptid * 4);
      float s = v.x + v.y + v.z + v.w;
      if (ptid == 0) s -= v.x;
      klacc += s;
    }
  }
  __syncthreads();

  if (tid_h < 64) {                                // pipeline prologue (once)
    #pragma unroll
    for (int j = 0; j < 4; ++j) {
      fA[j] = rows[half][0][j][tgA];
      fB[j] = rows[half][0][j][tgB];
      fK[j] = rows[half][0][j][0];
    }
  }

  float* pc = &rows[half][0][0][0];
  float* pn = &rows[half][1][0][0];
  float* pf = &rows[half][2][0][0];

  for (int p = 0; p < NPH; ++p) {
    if (tid_h < 64) {
      if (PH_ROWS * p + PH_ROWS + 1 <= Tb) {
        // FAST phase: all 16 steps active, branch-free
        #pragma unroll
        for (int k = 0; k < PH_ROWS; ++k) { CTC_STEP(k); }
      } else {
        // tail / short-length phase: per-step guard
        #pragma unroll
        for (int k = 0; k < PH_ROWS; ++k) {
          const int t = 1 + PH_ROWS * p + k;
          if (t < Tb) { CTC_STEP(k); }
        }
      }
    } else {
      // producers: fill pf with rows t = 33+16p .. 48+16p (as probs)
      const int ptid = tid_h - 64;
      const int t0 = 33 + PH_ROWS * p;
      if (t0 < T_DIM) {
        #pragma unroll
        for (int i = 0; i < 3; ++i) {
          const int task = i * 192 + ptid;         // 16 rows x 32 float4
          if (task < 512) {
            const int row = task >> 5;
            const int c4  = task & 31;
            const int t   = t0 + row;
            if (t < T_DIM) {
              const float4 v = *(const float4*)(base + (size_t)t * RSTR + c4 * 4);
              float4 w;
              w.x = __builtin_amdgcn_exp2f(v.x * LOG2E);
              w.y = __builtin_amdgcn_exp2f(v.y * LOG2E);
              w.z = __builtin_amdgcn_exp2f(v.z * LOG2E);
              w.w = __builtin_amdgcn_exp2f(v.w * LOG2E);
              *(float4*)&pf[row * C_DIM + c4 * 4] = w;
              if (t < Tb) {
                float s = v.x + v.y + v.z + v.w;
                if (c4 == 0) s -= v.x;
                klacc += s;
              }
            }
          }
        }
      }
    }
    __syncthreads();
    float* tmp = pc; pc = pn; pn = pf; pf = tmp;   // rotate ring
  }

  // ---------------- epilogue: reuse ring memory ----------------
  float* reg = &rows[half][0][0][0];
  float* als = reg;                                // 257 floats
  float* klr = reg + 272;                          // 3 floats
  if (tid_h < 64) {
    const int l = tid_h;
    const float Ef = (float)E;                     // |E| <~ 5e4: exact
    als[4 * l + 0] = __builtin_amdgcn_logf(r0) + Ef;
    als[4 * l + 1] = __builtin_amdgcn_logf(r1) + Ef;
    als[4 * l + 2] = __builtin_amdgcn_logf(r2) + Ef;
    als[4 * l + 3] = __builtin_amdgcn_logf(r3) + Ef;
    if (l == 63) als[256] = __builtin_amdgcn_logf(r4) + Ef;
  } else {
    float tot = klacc;
    tot += __shfl_xor(tot, 1, 64);
    tot += __shfl_xor(tot, 2, 64);
    tot += __shfl_xor(tot, 4, 64);
    tot += __shfl_xor(tot, 8, 64);
    tot += __shfl_xor(tot, 16, 64);
    tot += __shfl_xor(tot, 32, 64);
    if ((tid_h & 63) == 0) klr[(tid_h >> 6) - 1] = tot;
  }
  __syncthreads();
  if (tid_h == 0) {
    const int Lt = tg_len[b];
    const float xa = als[2 * Lt], xb = als[2 * Lt - 1];  // log2 domain
    const float mm = fmaxf(xa, xb);
    float loss = 0.f;
    if (mm > -1e30f) {
      loss = -((mm + __builtin_amdgcn_logf(
          __builtin_amdgcn_exp2f(xa - mm) + __builtin_amdgcn_exp2f(xb - mm))) * LN2);
    }
    ws[b] = loss;                                  // zero_infinity: loss 0
    ws[B_DIM + b] = klr[0] + klr[1] + klr[2];
  }
}

__global__ __launch_bounds__(128) void ctc_finalize_kernel(
    const float* __restrict__ ws, const int* __restrict__ in_len,
    float* __restrict__ out)
{
  __shared__ float red[128];
  const int tid = threadIdx.x;
  float v = 0.0f;
  if (tid < B_DIM) {
    const float ctc  = ws[tid];
    const float kls  = ws[B_DIM + tid];
    const float u    = 1.0f / (C_DIM - 1);
    const float logu = -4.8441870864585910f;       // log(1/127)
    const float klmean = logu - u * kls / (float)in_len[tid];
    v = (1.0f - SMOOTH) * ctc + SMOOTH * klmean;
  }
  red[tid] = v;
  __syncthreads();
  for (int off = 64; off > 0; off >>= 1) {
    if (tid < off) red[tid] += red[tid + off];
    __syncthreads();
  }
  if (tid == 0) out[0] = red[0] / (float)B_DIM;
}

extern "C" void kernel_launch(void* const* d_in, const int* in_sizes, int n_in,
                              void* d_out, int out_size, void* d_ws, size_t ws_size,
                              hipStream_t stream) {
  const float* lp      = (const float*)d_in[0];
  const int* targets   = (const int*)d_in[1];
  const int* in_len    = (const int*)d_in[2];
  const int* tg_len    = (const int*)d_in[3];
  float* ws  = (float*)d_ws;
  float* out = (float*)d_out;

  hipLaunchKernelGGL(ctc_fused_kernel, dim3(B_DIM / 2), dim3(512), 0, stream,
                     lp, targets, in_len, tg_len, ws);
  hipLaunchKernelGGL(ctc_finalize_kernel, dim3(1), dim3(128), 0, stream,
                     ws, in_len, out);
}

// Round 13
// 157.038 us; speedup vs baseline: 1.4781x; 1.4781x over previous
//
#include <hip/hip_runtime.h>
#include <math.h>

#define T_DIM 2048
#define B_DIM 96
#define C_DIM 128
#define L_DIM 128
#define LOG2E 1.4426950408889634f
#define LN2 0.69314718055994531f
#define SMOOTH 0.1f
#define SENT (-(1 << 30))       // virgin lane frame (f32-exact power of 2)
#define NPH 64                  // 64 phases x 32 steps cover t = 1..2047

// wave shift-right-by-1, 0-fill — the proven helper (float only).
__device__ __forceinline__ float dpp_shr1_f(float x) {
  return __int_as_float(__builtin_amdgcn_update_dpp(
      0, __float_as_int(x), 0x138 /*WAVE_SR1*/, 0xF, 0xF, true));
}

// R9/R10-proven CTC step math (unchanged). k_ is a compile-time unroll index.
#define CTC_STEP(kk_) do {                                                   \
  const int k_ = (kk_);                                                      \
  const float pAv = fA[k_ & 7], pBv = fB[k_ & 7], pKv = fK[k_ & 7];          \
  {                                                                          \
    const int kn = k_ + 8;                         /* depth-8 prefetch */    \
    const float* nr = (kn < 32) ? (pc + kn * C_DIM)                          \
                                : (pn + (kn - 32) * C_DIM);                  \
    fA[k_ & 7] = nr[tgA]; fB[k_ & 7] = nr[tgB]; fK[k_ & 7] = nr[0];          \
  }                                                                          \
  const float r3s = dpp_shr1_f(r3);                                          \
  const int   Es  = (int)dpp_shr1_f((float)E);                               \
  const int   be  = (__float_as_int(r3s) >> 23) & 0xFF;                      \
  int diff = (be - 187) + (Es - E);                                          \
  diff = (__float_as_int(r3s) != 0 && diff > 0) ? diff : 0;                  \
  r0 = ldexpf(r0, -diff); r1 = ldexpf(r1, -diff); r2 = ldexpf(r2, -diff);    \
  r3 = ldexpf(r3, -diff); r4 = ldexpf(r4, -diff);                            \
  E += diff;                                                                 \
  const float d3 = ldexpf(r3s, Es - E);                                      \
  const float n0 = (r0 + d3) * pKv;                                          \
  const float n1 = __builtin_fmaf(skA, d3, r0 + r1) * pAv;                   \
  const float n2 = (r2 + r1) * pKv;                                          \
  const float n3 = __builtin_fmaf(skB, r1, r3 + r2) * pBv;                   \
  const float n4 = (r4 + r3) * pKv;                                          \
  r0 = n0; r1 = n1; r2 = n2; r3 = n3; r4 = n4;                               \
  if ((k_ & 3) == 3) {                                                       \
    const float m = fmaxf(fmaxf(fmaxf(r0, r1), fmaxf(r2, r3)), r4);          \
    const int sh2 = (m > 0.0f)                                               \
                      ? (187 - ((__float_as_int(m) >> 23) & 0xFF)) : 0;      \
    r0 = ldexpf(r0, sh2); r1 = ldexpf(r1, sh2); r2 = ldexpf(r2, sh2);        \
    r3 = ldexpf(r3, sh2); r4 = ldexpf(r4, sh2);                              \
    E -= sh2;                                                                \
  }                                                                          \
} while (0)

// One block (256 thr) per sample b — R10 structure, depth-8 LDS pipeline.
//   wave 0   (consumer): CTC alpha recursion (R9 math), branch-free fast
//     phases, 24 live prefetch slots held in VGPRs.
//   waves1-3 (producer): stream rows coalesced, write p=exp2(lp*log2e) into a
//     triple-buffered LDS ring 2 phases ahead; accumulate KL from raw values.
__global__ __launch_bounds__(256) void ctc_fused_kernel(
    const float* __restrict__ lp, const int* __restrict__ targets,
    const int* __restrict__ in_len, const int* __restrict__ tg_len,
    float* __restrict__ ws)
{
  const int tid = threadIdx.x;
  const int b = blockIdx.x;
  const size_t RSTR = (size_t)B_DIM * C_DIM;       // floats per t-row
  const int Tb = in_len[b];
  const float* base = lp + (size_t)b * C_DIM;

  __shared__ float rows[3][32][C_DIM];             // 48 KB ring of PROBS
  __shared__ float als[257];
  __shared__ float klred[3];

  // consumer state
  int tgA = 0, tgB = 0;
  float skA = 0.f, skB = 0.f;
  float r0 = 0.f, r1 = 0.f, r2 = 0.f, r3 = 0.f, r4 = 0.f;
  int E = SENT;
  float fA[8], fB[8], fK[8];                       // depth-8 LDS pipeline
  float klacc = 0.f;                               // producers only

  if (tid < 64) {
    const int l = tid;
    tgA = targets[b * L_DIM + 2 * l];
    tgB = targets[b * L_DIM + 2 * l + 1];
    skA = (l > 0 && tgA != targets[b * L_DIM + 2 * l - 1]) ? 1.f : 0.f;
    skB = (tgB != tgA) ? 1.f : 0.f;
    if (l == 0) {
      r0 = __builtin_amdgcn_exp2f(base[0]   * LOG2E);
      r1 = __builtin_amdgcn_exp2f(base[tgA] * LOG2E);
      E = 0;
    }
  } else {
    // prefill rows t=1..64 (bufs 0,1) as PROBS; KL for t=0..64 from raw
    const int ptid = tid - 64;                     // 0..191
    #pragma unroll
    for (int i = 0; i < 11; ++i) {
      const int task = i * 192 + ptid;             // 64 rows x 32 float4
      if (task < 2048) {
        const int row = task >> 5;
        const int c4  = task & 31;
        const int t   = 1 + row;
        const float4 v = *(const float4*)(base + (size_t)t * RSTR + c4 * 4);
        float4 w;
        w.x = __builtin_amdgcn_exp2f(v.x * LOG2E);
        w.y = __builtin_amdgcn_exp2f(v.y * LOG2E);
        w.z = __builtin_amdgcn_exp2f(v.z * LOG2E);
        w.w = __builtin_amdgcn_exp2f(v.w * LOG2E);
        *(float4*)&rows[row >> 5][row & 31][c4 * 4] = w;
        if (t < Tb) {
          float s = v.x + v.y + v.z + v.w;
          if (c4 == 0) s -= v.x;
          klacc += s;
        }
      }
    }
    if (ptid < 32 && 0 < Tb) {                     // row 0 KL contribution
      const float4 v = *(const float4*)(base + ptid * 4);
      float s = v.x + v.y + v.z + v.w;
      if (ptid == 0) s -= v.x;
      klacc += s;
    }
  }
  __syncthreads();

  if (tid < 64) {                                  // pipeline prologue
    #pragma unroll
    for (int j = 0; j < 8; ++j) {
      fA[j] = rows[0][j][tgA]; fB[j] = rows[0][j][tgB]; fK[j] = rows[0][j][0];
    }
  }

  float* pc = &rows[0][0][0];
  float* pn = &rows[1][0][0];
  float* pf = &rows[2][0][0];

  for (int p = 0; p < NPH; ++p) {
    if (tid < 64) {
      if (32 * p + 33 <= Tb) {
        // -------- FAST phase: all 32 steps active, branch-free --------
        #pragma unroll
        for (int k = 0; k < 32; ++k) { CTC_STEP(k); }
      } else {
        // -------- tail / short-length phase: per-step guard --------
        #pragma unroll
        for (int k = 0; k < 32; ++k) {
          const int t = 1 + 32 * p + k;
          if (t < Tb) { CTC_STEP(k); }
        }
      }
    } else {
      // -------- producers: fill phase p+2 with PROBS --------
      const int ptid = tid - 64;
      const int t0 = 65 + 32 * p;
      if (t0 < T_DIM) {
        #pragma unroll
        for (int i = 0; i < 6; ++i) {
          const int task = i * 192 + ptid;         // 32 rows x 32 float4
          if (task < 1024) {
            const int row = task >> 5;
            const int c4  = task & 31;
            const int t   = t0 + row;
            if (t < T_DIM) {
              const float4 v = *(const float4*)(base + (size_t)t * RSTR + c4 * 4);
              float4 w;
              w.x = __builtin_amdgcn_exp2f(v.x * LOG2E);
              w.y = __builtin_amdgcn_exp2f(v.y * LOG2E);
              w.z = __builtin_amdgcn_exp2f(v.z * LOG2E);
              w.w = __builtin_amdgcn_exp2f(v.w * LOG2E);
              *(float4*)&pf[row * C_DIM + c4 * 4] = w;
              if (t < Tb) {
                float s = v.x + v.y + v.z + v.w;
                if (c4 == 0) s -= v.x;
                klacc += s;
              }
            }
          }
        }
      }
    }
    __syncthreads();
    float* tmp = pc; pc = pn; pn = pf; pf = tmp;   // rotate ring
  }

  // ---------------- epilogue ----------------
  if (tid < 64) {
    const int l = tid;
    const float Ef = (float)E;                     // |E| <~ 5e4: exact
    als[4 * l + 0] = __builtin_amdgcn_logf(r0) + Ef;
    als[4 * l + 1] = __builtin_amdgcn_logf(r1) + Ef;
    als[4 * l + 2] = __builtin_amdgcn_logf(r2) + Ef;
    als[4 * l + 3] = __builtin_amdgcn_logf(r3) + Ef;
    if (l == 63) als[256] = __builtin_amdgcn_logf(r4) + Ef;
  } else {
    float tot = klacc;
    tot += __shfl_xor(tot, 1, 64);
    tot += __shfl_xor(tot, 2, 64);
    tot += __shfl_xor(tot, 4, 64);
    tot += __shfl_xor(tot, 8, 64);
    tot += __shfl_xor(tot, 16, 64);
    tot += __shfl_xor(tot, 32, 64);
    if ((tid & 63) == 0) klred[(tid >> 6) - 1] = tot;
  }
  __syncthreads();
  if (tid == 0) {
    const int Lt = tg_len[b];
    const float xa = als[2 * Lt], xb = als[2 * Lt - 1];  // log2 domain
    const float mm = fmaxf(xa, xb);
    float loss = 0.f;
    if (mm > -1e30f) {
      loss = -((mm + __builtin_amdgcn_logf(
          __builtin_amdgcn_exp2f(xa - mm) + __builtin_amdgcn_exp2f(xb - mm))) * LN2);
    }
    ws[b] = loss;                                  // zero_infinity: loss 0
    ws[B_DIM + b] = klred[0] + klred[1] + klred[2];
  }
}

__global__ __launch_bounds__(128) void ctc_finalize_kernel(
    const float* __restrict__ ws, const int* __restrict__ in_len,
    float* __restrict__ out)
{
  __shared__ float red[128];
  const int tid = threadIdx.x;
  float v = 0.0f;
  if (tid < B_DIM) {
    const float ctc  = ws[tid];
    const float kls  = ws[B_DIM + tid];
    const float u    = 1.0f / (C_DIM - 1);
    const float logu = -4.8441870864585910f;       // log(1/127)
    const float klmean = logu - u * kls / (float)in_len[tid];
    v = (1.0f - SMOOTH) * ctc + SMOOTH * klmean;
  }
  red[tid] = v;
  __syncthreads();
  for (int off = 64; off > 0; off >>= 1) {
    if (tid < off) red[tid] += red[tid + off];
    __syncthreads();
  }
  if (tid == 0) out[0] = red[0] / (float)B_DIM;
}

extern "C" void kernel_launch(void* const* d_in, const int* in_sizes, int n_in,
                              void* d_out, int out_size, void* d_ws, size_t ws_size,
                              hipStream_t stream) {
  const float* lp      = (const float*)d_in[0];
  const int* targets   = (const int*)d_in[1];
  const int* in_len    = (const int*)d_in[2];
  const int* tg_len    = (const int*)d_in[3];
  float* ws  = (float*)d_ws;
  float* out = (float*)d_out;

  hipLaunchKernelGGL(ctc_fused_kernel, dim3(B_DIM), dim3(256), 0, stream,
                     lp, targets, in_len, tg_len, ws);
  hipLaunchKernelGGL(ctc_finalize_kernel, dim3(1), dim3(128), 0, stream,
                     ws, in_len, out);
}

// Round 14
// 88.676 us; speedup vs baseline: 2.6176x; 1.7709x over previous
//
#include <hip/hip_runtime.h>
#include <math.h>

#define T_DIM 2048
#define B_DIM 96
#define C_DIM 128
#define L_DIM 128
#define LOG2E 1.4426950408889634f
#define LN2 0.69314718055994531f
#define SMOOTH 0.1f
#define SENT (-(1 << 30))       // virgin lane frame (f32-exact power of 2)
#define NPH 32                  // 32 phases x 32 steps per half

// ws layout (floats)
#define AOFF 0                  // 96*257 alpha log2 values at t=1023
#define BOFF 24672              // 96*257 beta  log2 values at t=1023
#define KLA  49344              // 96 partial KL (rows 0..1023)
#define KLB  49440              // 96 partial KL (rows 1024..2047)
#define LOSS 49536              // 96 per-sample losses

// wave shift-right-by-1 / shift-left-by-1, 0-fill (proven helper class).
__device__ __forceinline__ float dpp_shr1_f(float x) {
  return __int_as_float(__builtin_amdgcn_update_dpp(
      0, __float_as_int(x), 0x138 /*WAVE_SR1*/, 0xF, 0xF, true));
}
__device__ __forceinline__ float dpp_shl1_f(float x) {
  return __int_as_float(__builtin_amdgcn_update_dpp(
      0, __float_as_int(x), 0x130 /*WAVE_SL1*/, 0xF, 0xF, true));
}

// R9/R10-proven ALPHA step math (unchanged), depth-4 prefetch.
#define ALPHA_STEP(kk_) do {                                                 \
  const int k_ = (kk_);                                                      \
  const float pAv = fA[k_ & 3], pBv = fB[k_ & 3], pKv = fK[k_ & 3];          \
  {                                                                          \
    const int kn = k_ + 4;                                                   \
    const float* nr = (kn < 32) ? (pc + kn * C_DIM)                          \
                                : (pn + (kn - 32) * C_DIM);                  \
    fA[k_ & 3] = nr[tgA]; fB[k_ & 3] = nr[tgB]; fK[k_ & 3] = nr[0];          \
  }                                                                          \
  const float r3s = dpp_shr1_f(r3);                                          \
  const int   Es  = (int)dpp_shr1_f((float)E);                               \
  const int   be  = (__float_as_int(r3s) >> 23) & 0xFF;                      \
  int diff = (be - 187) + (Es - E);                                          \
  diff = (__float_as_int(r3s) != 0 && diff > 0) ? diff : 0;                  \
  r0 = ldexpf(r0, -diff); r1 = ldexpf(r1, -diff); r2 = ldexpf(r2, -diff);    \
  r3 = ldexpf(r3, -diff); r4 = ldexpf(r4, -diff);                            \
  E += diff;                                                                 \
  const float d3 = ldexpf(r3s, Es - E);                                      \
  const float n0 = (r0 + d3) * pKv;                                          \
  const float n1 = __builtin_fmaf(skA, d3, r0 + r1) * pAv;                   \
  const float n2 = (r2 + r1) * pKv;                                          \
  const float n3 = __builtin_fmaf(skB, r1, r3 + r2) * pBv;                   \
  const float n4 = (r4 + r3) * pKv;                                          \
  r0 = n0; r1 = n1; r2 = n2; r3 = n3; r4 = n4;                               \
  if ((k_ & 3) == 3) {                                                       \
    const float m = fmaxf(fmaxf(fmaxf(r0, r1), fmaxf(r2, r3)), r4);          \
    const int sh2 = (m > 0.0f)                                               \
                      ? (187 - ((__float_as_int(m) >> 23) & 0xFF)) : 0;      \
    r0 = ldexpf(r0, sh2); r1 = ldexpf(r1, sh2); r2 = ldexpf(r2, sh2);        \
    r3 = ldexpf(r3, sh2); r4 = ldexpf(r4, sh2);                              \
    E -= sh2;                                                                \
  }                                                                          \
} while (0)

// BETA step: mirror (shift-left crossing of r1; gamma = p*beta products).
#define BETA_STEP(kk_) do {                                                  \
  const int k_ = (kk_);                                                      \
  const float pAv = fA[k_ & 3], pBv = fB[k_ & 3], pKv = fK[k_ & 3];          \
  const float pNv = fN[k_ & 3];                                              \
  {                                                                          \
    const int kn = k_ + 4;                                                   \
    const float* nr = (kn < 32) ? (pc + kn * C_DIM)                          \
                                : (pn + (kn - 32) * C_DIM);                  \
    fA[k_ & 3] = nr[tgA]; fB[k_ & 3] = nr[tgB]; fK[k_ & 3] = nr[0];          \
    fN[k_ & 3] = nr[tgAn];                                                   \
  }                                                                          \
  const float r1s = dpp_shl1_f(r1);                                          \
  const int   Es  = (int)dpp_shl1_f((float)E);                               \
  const int   be  = (__float_as_int(r1s) >> 23) & 0xFF;                      \
  int diff = (be - 187) + (Es - E);                                          \
  diff = (__float_as_int(r1s) != 0 && diff > 0) ? diff : 0;                  \
  r0 = ldexpf(r0, -diff); r1 = ldexpf(r1, -diff); r2 = ldexpf(r2, -diff);    \
  r3 = ldexpf(r3, -diff); r4 = ldexpf(r4, -diff);                            \
  E += diff;                                                                 \
  const float d5 = ldexpf(r1s, Es - E);                                      \
  const float g0 = r0 * pKv, g1 = r1 * pAv, g2 = r2 * pKv;                   \
  const float g3 = r3 * pBv, g4 = r4 * pKv, g5 = d5 * pNv;                   \
  const float n0 = g0 + g1;                                                  \
  const float n1 = __builtin_fmaf(skAp, g3, g1 + g2);                        \
  const float n2 = g2 + g3;                                                  \
  const float n3 = __builtin_fmaf(skBp, g5, g3 + g4);                        \
  const float n4 = g4 + g5;                                                  \
  r0 = n0; r1 = n1; r2 = n2; r3 = n3; r4 = n4;                               \
  if ((k_ & 3) == 3) {                                                       \
    const float m = fmaxf(fmaxf(fmaxf(r0, r1), fmaxf(r2, r3)), r4);          \
    const int sh2 = (m > 0.0f)                                               \
                      ? (187 - ((__float_as_int(m) >> 23) & 0xFF)) : 0;      \
    r0 = ldexpf(r0, sh2); r1 = ldexpf(r1, sh2); r2 = ldexpf(r2, sh2);        \
    r3 = ldexpf(r3, sh2); r4 = ldexpf(r4, sh2);                              \
    E -= sh2;                                                                \
  }                                                                          \
} while (0)

// Blocks 0..95: ALPHA half (t=0..1023). Blocks 96..191: BETA half (rows
// 2047..1024). Each block: wave0 = recursion consumer; waves1-3 = producers
// (stream rows coalesced, pre-exponentiate into 3-deep LDS ring, KL sum).
__global__ __launch_bounds__(256) void ctc_fused_kernel(
    const float* __restrict__ lp, const int* __restrict__ targets,
    const int* __restrict__ in_len, const int* __restrict__ tg_len,
    float* __restrict__ ws)
{
  const int tid = threadIdx.x;
  const int bid = blockIdx.x;
  const int isBeta = (bid >= B_DIM);
  const int b = isBeta ? bid - B_DIM : bid;
  const size_t RSTR = (size_t)B_DIM * C_DIM;       // floats per t-row
  const int Tb = in_len[b];
  const float* base = lp + (size_t)b * C_DIM;

  __shared__ float rows[3][32][C_DIM];             // 48 KB ring of PROBS
  __shared__ float klred[3];

  float klacc = 0.f;                               // producers only

  if (!isBeta) {
    // ================= ALPHA half =================
    const int TbA = (Tb < 1024) ? Tb : 1024;
    int tgA = 0, tgB = 0;
    float skA = 0.f, skB = 0.f;
    float r0 = 0.f, r1 = 0.f, r2 = 0.f, r3 = 0.f, r4 = 0.f;
    int E = SENT;
    float fA[4], fB[4], fK[4];

    if (tid < 64) {
      const int l = tid;
      tgA = targets[b * L_DIM + 2 * l];
      tgB = targets[b * L_DIM + 2 * l + 1];
      skA = (l > 0 && tgA != targets[b * L_DIM + 2 * l - 1]) ? 1.f : 0.f;
      skB = (tgB != tgA) ? 1.f : 0.f;
      if (l == 0) {
        r0 = __builtin_amdgcn_exp2f(base[0]   * LOG2E);
        r1 = __builtin_amdgcn_exp2f(base[tgA] * LOG2E);
        E = 0;
      }
    } else {
      // prefill rows t=1..64 as PROBS; KL for t=0..64
      const int ptid = tid - 64;
      #pragma unroll
      for (int i = 0; i < 11; ++i) {
        const int task = i * 192 + ptid;
        if (task < 2048) {
          const int row = task >> 5;
          const int c4  = task & 31;
          const int t   = 1 + row;
          const float4 v = *(const float4*)(base + (size_t)t * RSTR + c4 * 4);
          float4 w;
          w.x = __builtin_amdgcn_exp2f(v.x * LOG2E);
          w.y = __builtin_amdgcn_exp2f(v.y * LOG2E);
          w.z = __builtin_amdgcn_exp2f(v.z * LOG2E);
          w.w = __builtin_amdgcn_exp2f(v.w * LOG2E);
          *(float4*)&rows[row >> 5][row & 31][c4 * 4] = w;
          if (t < Tb) {
            float s = v.x + v.y + v.z + v.w;
            if (c4 == 0) s -= v.x;
            klacc += s;
          }
        }
      }
      if (ptid < 32 && 0 < Tb) {                   // row 0 KL
        const float4 v = *(const float4*)(base + ptid * 4);
        float s = v.x + v.y + v.z + v.w;
        if (ptid == 0) s -= v.x;
        klacc += s;
      }
    }
    __syncthreads();

    if (tid < 64) {
      #pragma unroll
      for (int j = 0; j < 4; ++j) {
        fA[j] = rows[0][j][tgA]; fB[j] = rows[0][j][tgB]; fK[j] = rows[0][j][0];
      }
    }
    float* pc = &rows[0][0][0];
    float* pn = &rows[1][0][0];
    float* pf = &rows[2][0][0];

    for (int p = 0; p < NPH; ++p) {
      if (tid < 64) {
        if (32 * p + 33 <= TbA) {
          #pragma unroll
          for (int k = 0; k < 32; ++k) { ALPHA_STEP(k); }
        } else {
          #pragma unroll
          for (int k = 0; k < 32; ++k) {
            const int t = 1 + 32 * p + k;
            if (t < TbA) { ALPHA_STEP(k); }
          }
        }
      } else {
        const int ptid = tid - 64;
        const int t0 = 65 + 32 * p;
        if (t0 <= 1023) {
          #pragma unroll
          for (int i = 0; i < 6; ++i) {
            const int task = i * 192 + ptid;
            if (task < 1024) {
              const int row = task >> 5;
              const int c4  = task & 31;
              const int t   = t0 + row;
              if (t <= 1023) {
                const float4 v = *(const float4*)(base + (size_t)t * RSTR + c4 * 4);
                float4 w;
                w.x = __builtin_amdgcn_exp2f(v.x * LOG2E);
                w.y = __builtin_amdgcn_exp2f(v.y * LOG2E);
                w.z = __builtin_amdgcn_exp2f(v.z * LOG2E);
                w.w = __builtin_amdgcn_exp2f(v.w * LOG2E);
                *(float4*)&pf[row * C_DIM + c4 * 4] = w;
                if (t < Tb) {
                  float s = v.x + v.y + v.z + v.w;
                  if (c4 == 0) s -= v.x;
                  klacc += s;
                }
              }
            }
          }
        }
      }
      __syncthreads();
      float* tmp = pc; pc = pn; pn = pf; pf = tmp;
    }

    // epilogue: alpha at t=1023 in absolute log2 -> ws
    if (tid < 64) {
      const int l = tid;
      const float Ef = (float)E;
      float* dst = ws + AOFF + b * 257;
      dst[4 * l + 0] = __builtin_amdgcn_logf(r0) + Ef;
      dst[4 * l + 1] = __builtin_amdgcn_logf(r1) + Ef;
      dst[4 * l + 2] = __builtin_amdgcn_logf(r2) + Ef;
      dst[4 * l + 3] = __builtin_amdgcn_logf(r3) + Ef;
      if (l == 63) dst[256] = __builtin_amdgcn_logf(r4) + Ef;
    } else {
      float tot = klacc;
      tot += __shfl_xor(tot, 1, 64);  tot += __shfl_xor(tot, 2, 64);
      tot += __shfl_xor(tot, 4, 64);  tot += __shfl_xor(tot, 8, 64);
      tot += __shfl_xor(tot, 16, 64); tot += __shfl_xor(tot, 32, 64);
      if ((tid & 63) == 0) klred[(tid >> 6) - 1] = tot;
    }
    __syncthreads();
    if (tid == 0) ws[KLA + b] = klred[0] + klred[1] + klred[2];

  } else {
    // ================= BETA half =================
    int tgA = 0, tgB = 0, tgAn = 0;
    float skAp = 0.f, skBp = 0.f;
    float r0 = 0.f, r1 = 0.f, r2 = 0.f, r3 = 0.f, r4 = 0.f;
    int E = SENT;
    float fA[4], fB[4], fK[4], fN[4];

    if (tid < 64) {
      const int l = tid;
      tgA = targets[b * L_DIM + 2 * l];
      tgB = targets[b * L_DIM + 2 * l + 1];
      const int nidx = (l < 63) ? (2 * l + 2) : (2 * l);   // lane l+1's tgA
      tgAn = targets[b * L_DIM + nidx];
      skAp = (tgB != tgA) ? 1.f : 0.f;
      skBp = (l < 63 && tgAn != tgB) ? 1.f : 0.f;
      // init beta_{2047}: 1 at s = 2Lt and 2Lt-1
      const int Lt = tg_len[b];
      const int s0 = 4 * l;
      r0 = (s0 == 2 * Lt || s0 == 2 * Lt - 1) ? 1.f : 0.f;
      r1 = (s0 + 1 == 2 * Lt || s0 + 1 == 2 * Lt - 1) ? 1.f : 0.f;
      r2 = (s0 + 2 == 2 * Lt || s0 + 2 == 2 * Lt - 1) ? 1.f : 0.f;
      r3 = (s0 + 3 == 2 * Lt || s0 + 3 == 2 * Lt - 1) ? 1.f : 0.f;
      r4 = (s0 + 4 == 2 * Lt || s0 + 4 == 2 * Lt - 1) ? 1.f : 0.f;
      E = (r0 + r1 + r2 + r3 + r4 > 0.f) ? 0 : SENT;
    } else {
      // prefill rows 2047..1984 as PROBS (slot j <- row 2047-j); KL guarded
      const int ptid = tid - 64;
      #pragma unroll
      for (int i = 0; i < 11; ++i) {
        const int task = i * 192 + ptid;
        if (task < 2048) {
          const int row = task >> 5;                // j = 0..63
          const int c4  = task & 31;
          const int t   = 2047 - row;
          const float4 v = *(const float4*)(base + (size_t)t * RSTR + c4 * 4);
          float4 w;
          w.x = __builtin_amdgcn_exp2f(v.x * LOG2E);
          w.y = __builtin_amdgcn_exp2f(v.y * LOG2E);
          w.z = __builtin_amdgcn_exp2f(v.z * LOG2E);
          w.w = __builtin_amdgcn_exp2f(v.w * LOG2E);
          *(float4*)&rows[row >> 5][row & 31][c4 * 4] = w;
          if (t < Tb) {
            float s = v.x + v.y + v.z + v.w;
            if (c4 == 0) s -= v.x;
            klacc += s;
          }
        }
      }
    }
    __syncthreads();

    if (tid < 64) {
      #pragma unroll
      for (int j = 0; j < 4; ++j) {
        fA[j] = rows[0][j][tgA]; fB[j] = rows[0][j][tgB];
        fK[j] = rows[0][j][0];   fN[j] = rows[0][j][tgAn];
      }
    }
    float* pc = &rows[0][0][0];
    float* pn = &rows[1][0][0];
    float* pf = &rows[2][0][0];

    for (int p = 0; p < NPH; ++p) {
      if (tid < 64) {
        const int rmax = 2047 - 32 * p;
        const int rmin = rmax - 31;
        if (rmax < Tb) {
          #pragma unroll
          for (int k = 0; k < 32; ++k) { BETA_STEP(k); }
        } else if (rmin < Tb) {
          #pragma unroll
          for (int k = 0; k < 32; ++k) {
            const int r = 2047 - 32 * p - k;
            if (r < Tb) { BETA_STEP(k); }
          }
        } // else fully frozen: no-op
      } else {
        const int ptid = tid - 64;
        const int t0 = 1983 - 32 * p;               // top row for phase p+2
        if (t0 >= 1024) {
          #pragma unroll
          for (int i = 0; i < 6; ++i) {
            const int task = i * 192 + ptid;
            if (task < 1024) {
              const int row = task >> 5;            // slot j
              const int c4  = task & 31;
              const int t   = t0 - row;
              if (t >= 1024) {
                const float4 v = *(const float4*)(base + (size_t)t * RSTR + c4 * 4);
                float4 w;
                w.x = __builtin_amdgcn_exp2f(v.x * LOG2E);
                w.y = __builtin_amdgcn_exp2f(v.y * LOG2E);
                w.z = __builtin_amdgcn_exp2f(v.z * LOG2E);
                w.w = __builtin_amdgcn_exp2f(v.w * LOG2E);
                *(float4*)&pf[row * C_DIM + c4 * 4] = w;
                if (t < Tb) {
                  float s = v.x + v.y + v.z + v.w;
                  if (c4 == 0) s -= v.x;
                  klacc += s;
                }
              }
            }
          }
        }
      }
      __syncthreads();
      float* tmp = pc; pc = pn; pn = pf; pf = tmp;
    }

    // epilogue: beta at t=1023 in absolute log2 -> ws
    if (tid < 64) {
      const int l = tid;
      const float Ef = (float)E;
      float* dst = ws + BOFF + b * 257;
      dst[4 * l + 0] = __builtin_amdgcn_logf(r0) + Ef;
      dst[4 * l + 1] = __builtin_amdgcn_logf(r1) + Ef;
      dst[4 * l + 2] = __builtin_amdgcn_logf(r2) + Ef;
      dst[4 * l + 3] = __builtin_amdgcn_logf(r3) + Ef;
      if (l == 63) dst[256] = __builtin_amdgcn_logf(r4) + Ef;
    } else {
      float tot = klacc;
      tot += __shfl_xor(tot, 1, 64);  tot += __shfl_xor(tot, 2, 64);
      tot += __shfl_xor(tot, 4, 64);  tot += __shfl_xor(tot, 8, 64);
      tot += __shfl_xor(tot, 16, 64); tot += __shfl_xor(tot, 32, 64);
      if ((tid & 63) == 0) klred[(tid >> 6) - 1] = tot;
    }
    __syncthreads();
    if (tid == 0) ws[KLB + b] = klred[0] + klred[1] + klred[2];
  }
}

// Per-sample combine: ll = logsumexp_s(alpha_log2[s] + beta_log2[s]); loss.
__global__ __launch_bounds__(64) void ctc_combine_kernel(
    const float* __restrict__ ws_in, const int* __restrict__ in_len,
    float* __restrict__ ws_out)
{
  const int b = blockIdx.x;
  const int l = threadIdx.x;
  const float* a  = ws_in + AOFF + b * 257;
  const float* bb = ws_in + BOFF + b * 257;
  float x0 = a[4 * l + 0] + bb[4 * l + 0];
  float x1 = a[4 * l + 1] + bb[4 * l + 1];
  float x2 = a[4 * l + 2] + bb[4 * l + 2];
  float x3 = a[4 * l + 3] + bb[4 * l + 3];
  float x4 = (l == 63) ? (a[256] + bb[256]) : -3.0e38f;
  float m = fmaxf(fmaxf(fmaxf(x0, x1), fmaxf(x2, x3)), x4);
  m = fmaxf(m, __shfl_xor(m, 1, 64));  m = fmaxf(m, __shfl_xor(m, 2, 64));
  m = fmaxf(m, __shfl_xor(m, 4, 64));  m = fmaxf(m, __shfl_xor(m, 8, 64));
  m = fmaxf(m, __shfl_xor(m, 16, 64)); m = fmaxf(m, __shfl_xor(m, 32, 64));
  const float ms = fmaxf(m, -1.0e37f);
  float s = __builtin_amdgcn_exp2f(x0 - ms) + __builtin_amdgcn_exp2f(x1 - ms)
          + __builtin_amdgcn_exp2f(x2 - ms) + __builtin_amdgcn_exp2f(x3 - ms)
          + __builtin_amdgcn_exp2f(x4 - ms);
  s += __shfl_xor(s, 1, 64);  s += __shfl_xor(s, 2, 64);
  s += __shfl_xor(s, 4, 64);  s += __shfl_xor(s, 8, 64);
  s += __shfl_xor(s, 16, 64); s += __shfl_xor(s, 32, 64);
  if (l == 0) {
    float ctc = 0.f;
    if (s > 0.f && m > -1.0e30f) {
      ctc = -((ms + __builtin_amdgcn_logf(s)) * LN2);
    }
    const int Tb = in_len[b];
    const float u    = 1.0f / (C_DIM - 1);
    const float logu = -4.8441870864585910f;       // log(1/127)
    const float kls  = ws_in[KLA + b] + ws_in[KLB + b];
    const float klmean = logu - u * kls / (float)Tb;
    ws_out[LOSS + b] = (1.0f - SMOOTH) * ctc + SMOOTH * klmean;
  }
}

__global__ __launch_bounds__(128) void ctc_mean_kernel(
    const float* __restrict__ ws, float* __restrict__ out)
{
  __shared__ float red[128];
  const int tid = threadIdx.x;
  red[tid] = (tid < B_DIM) ? ws[LOSS + tid] : 0.f;
  __syncthreads();
  for (int off = 64; off > 0; off >>= 1) {
    if (tid < off) red[tid] += red[tid + off];
    __syncthreads();
  }
  if (tid == 0) out[0] = red[0] / (float)B_DIM;
}

extern "C" void kernel_launch(void* const* d_in, const int* in_sizes, int n_in,
                              void* d_out, int out_size, void* d_ws, size_t ws_size,
                              hipStream_t stream) {
  const float* lp      = (const float*)d_in[0];
  const int* targets   = (const int*)d_in[1];
  const int* in_len    = (const int*)d_in[2];
  const int* tg_len    = (const int*)d_in[3];
  float* ws  = (float*)d_ws;
  float* out = (float*)d_out;

  hipLaunchKernelGGL(ctc_fused_kernel, dim3(2 * B_DIM), dim3(256), 0, stream,
                     lp, targets, in_len, tg_len, ws);
  hipLaunchKernelGGL(ctc_combine_kernel, dim3(B_DIM), dim3(64), 0, stream,
                     ws, in_len, ws);
  hipLaunchKernelGGL(ctc_mean_kernel, dim3(1), dim3(128), 0, stream,
                     ws, out);
}